// Round 2
// baseline (371.270 us; speedup 1.0000x reference)
//
#include <hip/hip_runtime.h>

// Problem constants
constexpr int Bn = 32, Tn = 8, Cn = 1024, Sn = 4096, Hn = 16, HDn = 64;
constexpr int NCHUNK = 16;      // 4096 / 256 keys per chunk-block
constexpr int KSPLIT = 4;       // K-split for the 256x1024x1024 GEMMs
constexpr float SCALE = 0.125f; // 1/sqrt(64)

// Workspace layout (in floats)
constexpr size_t PROJ_PART = (size_t)Bn * Tn * Cn;          // 262144 (one partial)
constexpr size_t QP_OFF = 0;
constexpr size_t KP_OFF = QP_OFF + KSPLIT * PROJ_PART;
constexpr size_t VP_OFF = KP_OFF + KSPLIT * PROJ_PART;
constexpr size_t PACC_OFF = VP_OFF + KSPLIT * PROJ_PART;
constexpr size_t PACC_SZ = (size_t)NCHUNK * Bn * Hn * Tn * HDn;
constexpr size_t PL_OFF = PACC_OFF + PACC_SZ;
constexpr size_t PL_SZ = (size_t)NCHUNK * Bn * Hn * Tn;
constexpr size_t AW_OFF = PL_OFF + PL_SZ;
constexpr size_t AW_SZ = (size_t)Bn * Tn * Cn;
constexpr size_t OP_OFF = AW_OFF + AW_SZ;
constexpr size_t OP_SZ = (size_t)KSPLIT * PROJ_PART;

// ---------------- GEMM: Y_partial[sigma] = X(256xK-slice) @ W^T ----------------
// Block: 256 thr. Tile: 64 rows x 64 cols. Per-thread 4x4 register tile.
// Grid z carries K-split sigma (and weight id for proj3).
__device__ __forceinline__ void gemm_body(const float* __restrict__ X,
                                          const float* __restrict__ W,
                                          float* __restrict__ Opart,
                                          int sigma, int jblk, int iblk) {
    __shared__ float wl[64][68]; // [k][j], pad 68
    const int tid = threadIdx.x;
    const int c = tid & 15, a = tid >> 4;
    const int j0 = jblk * 64;
    const int ib = iblk * 64 + a * 4;
    const int k0 = sigma * 256;

    float acc[4][4];
#pragma unroll
    for (int ii = 0; ii < 4; ++ii)
#pragma unroll
        for (int jj = 0; jj < 4; ++jj) acc[ii][jj] = 0.f;

    for (int kt = 0; kt < 4; ++kt) {
        const int k1 = k0 + kt * 64;
#pragma unroll
        for (int stp = 0; stp < 4; ++stp) {
            int f4 = stp * 256 + tid;
            int jr = f4 >> 4, e4 = f4 & 15;
            float4 wv = *(const float4*)&W[(size_t)(j0 + jr) * Cn + k1 + e4 * 4];
            wl[e4 * 4 + 0][jr] = wv.x;
            wl[e4 * 4 + 1][jr] = wv.y;
            wl[e4 * 4 + 2][jr] = wv.z;
            wl[e4 * 4 + 3][jr] = wv.w;
        }
        __syncthreads();
#pragma unroll 4
        for (int k4 = 0; k4 < 16; ++k4) {
            float4 xv[4];
#pragma unroll
            for (int ii = 0; ii < 4; ++ii)
                xv[ii] = *(const float4*)&X[(size_t)(ib + ii) * Cn + k1 + k4 * 4];
#pragma unroll
            for (int kk = 0; kk < 4; ++kk) {
                float4 wv = *(const float4*)&wl[k4 * 4 + kk][c * 4];
#pragma unroll
                for (int ii = 0; ii < 4; ++ii) {
                    const float xs = (kk == 0) ? xv[ii].x : (kk == 1) ? xv[ii].y
                                   : (kk == 2) ? xv[ii].z : xv[ii].w;
                    acc[ii][0] += xs * wv.x;
                    acc[ii][1] += xs * wv.y;
                    acc[ii][2] += xs * wv.z;
                    acc[ii][3] += xs * wv.w;
                }
            }
        }
        __syncthreads();
    }
    float* op = Opart + (size_t)sigma * PROJ_PART;
#pragma unroll
    for (int ii = 0; ii < 4; ++ii) {
        float4 o = make_float4(acc[ii][0], acc[ii][1], acc[ii][2], acc[ii][3]);
        *(float4*)&op[(size_t)(ib + ii) * Cn + j0 + c * 4] = o;
    }
}

__global__ __launch_bounds__(256) void proj3_kernel(
    const float* __restrict__ X, const float* __restrict__ W0,
    const float* __restrict__ W1, const float* __restrict__ W2,
    float* __restrict__ O0, float* __restrict__ O1, float* __restrict__ O2) {
    const int z = blockIdx.z;
    const float* W = (z < 4) ? W0 : (z < 8 ? W1 : W2);
    float* O = (z < 4) ? O0 : (z < 8 ? O1 : O2);
    gemm_body(X, W, O, z & 3, blockIdx.x, blockIdx.y);
}

__global__ __launch_bounds__(256) void gemm1_kernel(
    const float* __restrict__ X, const float* __restrict__ W, float* __restrict__ O) {
    gemm_body(X, W, O, blockIdx.z, blockIdx.x, blockIdx.y);
}

// ---------------- Attention partials: single-pass streaming, no LDS staging ----
// Grid (cq=16, h=16, b=32), block 256 = 4 independent waves, 64 key rows each.
// Lane layout: rg = lane>>4 (row residue 0..3), c4 = lane&15 (dim group).
// Per 4-row pass: coalesced 1KB b128 loads of K and V; score via 4x shfl_xor
// butterfly (bitwise-identical across the 16-lane group -> x16 exact, /16 later);
// p consumed immediately (no-max softmax => single fused QK+PV pass, no storage).
__global__ __launch_bounds__(256, 4) void attn_kernel(
    const float* __restrict__ qpart, const float* __restrict__ kpart,
    const float* __restrict__ vpart, const float* __restrict__ ck,
    const float* __restrict__ cv, const int* __restrict__ clen,
    float* __restrict__ pacc, float* __restrict__ pl) {
    const int cq = blockIdx.x, h = blockIdx.y, b = blockIdx.z;
    const int cl = clen[b];
    if (!(cq == 0 || cq * 256 < cl)) return; // uniform early exit

    const int tid = threadIdx.x, wave = tid >> 6, lane = tid & 63;
    const int rg = lane >> 4;  // row residue 0..3
    const int c4 = lane & 15;  // dim group (4 floats)

    __shared__ float redacc[4][8][64]; // 8KB block-reduce buffer
    __shared__ float redl[4][8];

    // q fragment: q[t][c4*4 .. +4), summed over 4 K-split partials
    float4 qf[8];
    {
        const float* qb = qpart + (size_t)b * Tn * Cn + h * HDn + c4 * 4;
#pragma unroll
        for (int t = 0; t < 8; ++t) {
            const float* s0 = qb + (size_t)t * Cn;
            float4 a0 = *(const float4*)(s0);
            float4 a1 = *(const float4*)(s0 + PROJ_PART);
            float4 a2 = *(const float4*)(s0 + 2 * PROJ_PART);
            float4 a3 = *(const float4*)(s0 + 3 * PROJ_PART);
            qf[t] = make_float4(a0.x + a1.x + a2.x + a3.x, a0.y + a1.y + a2.y + a3.y,
                                a0.z + a1.z + a2.z + a3.z, a0.w + a1.w + a2.w + a3.w);
        }
    }

    const int r0 = cq * 256 + wave * 64;
    int n_valid = cl - r0;
    n_valid = n_valid < 0 ? 0 : (n_valid > 64 ? 64 : n_valid);

    float lden[8], av[8][4];
#pragma unroll
    for (int t = 0; t < 8; ++t) {
        lden[t] = 0.f;
        av[t][0] = av[t][1] = av[t][2] = av[t][3] = 0.f;
    }

    if (n_valid > 0) {
        const float* kb = ck + ((size_t)b * Sn + r0 + rg) * Cn + h * HDn + c4 * 4;
        const float* vb = cv + ((size_t)b * Sn + r0 + rg) * Cn + h * HDn + c4 * 4;
#pragma unroll 2
        for (int i = 0; i < 16; ++i) {
            const int row = i * 4 + rg;
            const float4 kv = *(const float4*)(kb + (size_t)i * 4 * Cn);
            const float4 vv = *(const float4*)(vb + (size_t)i * 4 * Cn);
            const bool val = row < n_valid;
#pragma unroll
            for (int t = 0; t < 8; ++t) {
                float s = kv.x * qf[t].x + kv.y * qf[t].y + kv.z * qf[t].z + kv.w * qf[t].w;
                s += __shfl_xor(s, 1);
                s += __shfl_xor(s, 2);
                s += __shfl_xor(s, 4);
                s += __shfl_xor(s, 8);
                const float p = val ? __expf(s * SCALE) : 0.f;
                lden[t] += p;
                av[t][0] += p * vv.x;
                av[t][1] += p * vv.y;
                av[t][2] += p * vv.z;
                av[t][3] += p * vv.w;
            }
        }
    }

    if (cq == 0 && wave == 0) {
        // max(cache_len) for the zero-pad denominator term
        int mv = clen[lane & 31];
#pragma unroll
        for (int off = 16; off >= 1; off >>= 1) {
            int o = __shfl_xor(mv, off);
            mv = mv > o ? mv : o;
        }
        const int pad = mv - cl;
        const float* kb = kpart + ((size_t)b * Tn + rg) * Cn + h * HDn + c4 * 4;
        const float* vbp = vpart + ((size_t)b * Tn + rg) * Cn + h * HDn + c4 * 4;
#pragma unroll
        for (int i = 0; i < 2; ++i) { // 8 new-key rows
            const float* ks = kb + (size_t)i * 4 * Cn;
            const float* vs = vbp + (size_t)i * 4 * Cn;
            float4 k0 = *(const float4*)(ks);
            float4 k1 = *(const float4*)(ks + PROJ_PART);
            float4 k2 = *(const float4*)(ks + 2 * PROJ_PART);
            float4 k3 = *(const float4*)(ks + 3 * PROJ_PART);
            const float4 kv = make_float4(k0.x + k1.x + k2.x + k3.x, k0.y + k1.y + k2.y + k3.y,
                                          k0.z + k1.z + k2.z + k3.z, k0.w + k1.w + k2.w + k3.w);
            float4 v0 = *(const float4*)(vs);
            float4 v1 = *(const float4*)(vs + PROJ_PART);
            float4 v2 = *(const float4*)(vs + 2 * PROJ_PART);
            float4 v3 = *(const float4*)(vs + 3 * PROJ_PART);
            const float4 vv = make_float4(v0.x + v1.x + v2.x + v3.x, v0.y + v1.y + v2.y + v3.y,
                                          v0.z + v1.z + v2.z + v3.z, v0.w + v1.w + v2.w + v3.w);
#pragma unroll
            for (int t = 0; t < 8; ++t) {
                float s = kv.x * qf[t].x + kv.y * qf[t].y + kv.z * qf[t].z + kv.w * qf[t].w;
                s += __shfl_xor(s, 1);
                s += __shfl_xor(s, 2);
                s += __shfl_xor(s, 4);
                s += __shfl_xor(s, 8);
                const float p = __expf(s * SCALE);
                lden[t] += p;
                av[t][0] += p * vv.x;
                av[t][1] += p * vv.y;
                av[t][2] += p * vv.z;
                av[t][3] += p * vv.w;
            }
        }
        if (lane == 0) {
#pragma unroll
            for (int t = 0; t < 8; ++t) lden[t] += 16.f * (float)pad;
        }
    }

    // accv: sum over the 4 row-residue groups (lanes l, l^16, l^32, l^48)
#pragma unroll
    for (int t = 0; t < 8; ++t)
#pragma unroll
        for (int e = 0; e < 4; ++e) {
            av[t][e] += __shfl_xor(av[t][e], 16);
            av[t][e] += __shfl_xor(av[t][e], 32);
        }
    // lden: full 64-lane butterfly; each row counted 16x (exact) -> /16
#pragma unroll
    for (int t = 0; t < 8; ++t) {
        float v = lden[t];
#pragma unroll
        for (int off = 32; off >= 1; off >>= 1) v += __shfl_xor(v, off);
        lden[t] = v * (1.f / 16.f);
    }

    if (lane < 16) {
#pragma unroll
        for (int t = 0; t < 8; ++t)
            *(float4*)&redacc[wave][t][lane * 4] =
                make_float4(av[t][0], av[t][1], av[t][2], av[t][3]);
    }
    if (lane == 0) {
#pragma unroll
        for (int t = 0; t < 8; ++t) redl[wave][t] = lden[t];
    }
    __syncthreads();
    const size_t obase = (size_t)((cq * Bn + b) * Hn + h);
#pragma unroll
    for (int rep = 0; rep < 2; ++rep) {
        int e = rep * 256 + tid;
        int t = e >> 6, d = e & 63;
        float s = redacc[0][t][d] + redacc[1][t][d] + redacc[2][t][d] + redacc[3][t][d];
        pacc[obase * 512 + e] = s;
    }
    if (tid < 8) pl[obase * 8 + tid] = redl[0][tid] + redl[1][tid] + redl[2][tid] + redl[3][tid];
}

// ---------------- Merge chunk partials, normalize ----------------
__global__ __launch_bounds__(64) void attn_merge_kernel(
    const float* __restrict__ pacc, const float* __restrict__ pl,
    const int* __restrict__ clen, float* __restrict__ aw) {
    const int h = blockIdx.x, b = blockIdx.y, lane = threadIdx.x;
    const int cl = clen[b];
    int nch = (cl + 255) >> 8;
    if (nch < 1) nch = 1;
    float acc[8], l[8];
#pragma unroll
    for (int t = 0; t < 8; ++t) { acc[t] = 0.f; l[t] = 0.f; }
    for (int c = 0; c < nch; ++c) {
        const size_t base = (size_t)((c * Bn + b) * Hn + h);
#pragma unroll
        for (int t = 0; t < 8; ++t) acc[t] += pacc[base * 512 + t * 64 + lane];
#pragma unroll
        for (int t = 0; t < 8; ++t) l[t] += pl[base * 8 + t];
    }
#pragma unroll
    for (int t = 0; t < 8; ++t)
        aw[(size_t)(b * Tn + t) * Cn + h * HDn + lane] = acc[t] / l[t];
}

// ---------------- Sum final-GEMM partials + bias ----------------
__global__ __launch_bounds__(256) void bias_out_kernel(
    const float* __restrict__ opart, const float* __restrict__ bo, float* __restrict__ out) {
    const int f4 = blockIdx.x * 256 + threadIdx.x; // 65536 float4s
    const float4 a0 = *(const float4*)(opart + (size_t)f4 * 4);
    const float4 a1 = *(const float4*)(opart + PROJ_PART + (size_t)f4 * 4);
    const float4 a2 = *(const float4*)(opart + 2 * PROJ_PART + (size_t)f4 * 4);
    const float4 a3 = *(const float4*)(opart + 3 * PROJ_PART + (size_t)f4 * 4);
    const float4 bv = *(const float4*)&bo[(f4 & 255) * 4];
    float4 o = make_float4(a0.x + a1.x + a2.x + a3.x + bv.x,
                           a0.y + a1.y + a2.y + a3.y + bv.y,
                           a0.z + a1.z + a2.z + a3.z + bv.z,
                           a0.w + a1.w + a2.w + a3.w + bv.w);
    *(float4*)&((float*)out)[(size_t)f4 * 4] = o;
}

extern "C" void kernel_launch(void* const* d_in, const int* in_sizes, int n_in,
                              void* d_out, int out_size, void* d_ws, size_t ws_size,
                              hipStream_t stream) {
    const float* x  = (const float*)d_in[0];
    const float* ck = (const float*)d_in[1];
    const float* cv = (const float*)d_in[2];
    const int*   cl = (const int*)d_in[3];
    const float* wq = (const float*)d_in[4];
    const float* wk = (const float*)d_in[5];
    const float* wv = (const float*)d_in[6];
    const float* wo = (const float*)d_in[7];
    const float* bo = (const float*)d_in[8];
    float* out = (float*)d_out;
    float* ws = (float*)d_ws;

    float* qpart = ws + QP_OFF;
    float* kpart = ws + KP_OFF;
    float* vpart = ws + VP_OFF;
    float* pacc  = ws + PACC_OFF;
    float* pl    = ws + PL_OFF;
    float* aw    = ws + AW_OFF;
    float* opart = ws + OP_OFF;

    // 1) q/k/v projections (K-split-4 partials), 64x64 tiles, 768 blocks
    proj3_kernel<<<dim3(16, 4, 12), dim3(256), 0, stream>>>(x, wq, wk, wv, qpart, kpart, vpart);
    // 2) attention partials per (chunk, head, batch) — streaming single pass
    attn_kernel<<<dim3(NCHUNK, Hn, Bn), dim3(256), 0, stream>>>(qpart, kpart, vpart, ck, cv, cl, pacc, pl);
    // 3) merge + normalize
    attn_merge_kernel<<<dim3(Hn, Bn), dim3(64), 0, stream>>>(pacc, pl, cl, aw);
    // 4) output projection (K-split-4 partials), 256 blocks
    gemm1_kernel<<<dim3(16, 4, KSPLIT), dim3(256), 0, stream>>>(aw, wo, opart);
    // 5) sum partials + bias
    bias_out_kernel<<<dim3(256), dim3(256), 0, stream>>>(opart, bo, out);
}